// Round 2
// baseline (2734.810 us; speedup 1.0000x reference)
//
#include <hip/hip_runtime.h>

// Problem constants
#define V_  32000
#define E_  256
#define H_  256
#define S_  128
#define B_  64
#define HID_ 30

// Accurate f32 activations (<= ~1-2 ulp, matching numpy/jax f32 semantics class)
__device__ __forceinline__ float sigmoid_acc(float x) {
    return 1.0f / (1.0f + expf(-x));   // precise division (no fast-math)
}
__device__ __forceinline__ float tanh_acc(float x) {
    return tanhf(x);
}

// ---------------------------------------------------------------------------
// K1: f32 input-projection GEMM with fused embedding gather.
//   Xg[dir][m][g] = sum_k emb[concepts[m]][k] * Wih[g][k],  m = s*64+b
// M=8192, N=1024, K=256, 2 dirs. 64x64 tile, 4x4 per thread, KC=64 via LDS.
// grid (2048, 2), block 256.
// ---------------------------------------------------------------------------
#define KC_ 64
#define LDP_ 68   // LDS row stride (floats): 16B-aligned for float4 reads

__global__ __launch_bounds__(256) void gemm_f32_kernel(
    const int* __restrict__ concepts, const float* __restrict__ embedding,
    const float* __restrict__ Wih_f, const float* __restrict__ Wih_b,
    float* __restrict__ Xg) {
    __shared__ float Asub[KC_][LDP_];   // [k][m]
    __shared__ float Bsub[KC_][LDP_];   // [k][g]
    const int dir = blockIdx.y;
    const float* Wih = dir ? Wih_b : Wih_f;
    const int mt = blockIdx.x >> 4;     // 0..127
    const int nt = blockIdx.x & 15;     // 0..15
    const int m0 = mt * 64, n0 = nt * 64;
    const int t = threadIdx.x;
    const int lr = t >> 6;              // wave id 0..3 (row offset for loads)
    const int lk = t & 63;              // lane -> k (coalesced global reads)
    const int tm = (t & 15) * 4;        // compute: 4 m-rows
    const int tg = (t >> 4) * 4;        // compute: 4 g-cols

    float acc[4][4];
#pragma unroll
    for (int i = 0; i < 4; ++i)
#pragma unroll
        for (int j = 0; j < 4; ++j) acc[i][j] = 0.f;

    for (int kk = 0; kk < E_; kk += KC_) {
        __syncthreads();   // previous tiles fully consumed
#pragma unroll
        for (int p = 0; p < 16; ++p) {
            int r = 4 * p + lr;  // row within tile, wave-uniform
            // A: gathered embedding row (concepts[] is wave-uniform -> s_load)
            Asub[lk][r] = embedding[(size_t)concepts[m0 + r] * E_ + kk + lk];
            // B: Wih row g = n0 + r
            Bsub[lk][r] = Wih[(size_t)(n0 + r) * E_ + kk + lk];
        }
        __syncthreads();
#pragma unroll
        for (int k = 0; k < KC_; ++k) {
            float4 a = *(const float4*)&Asub[k][tm];
            float4 b = *(const float4*)&Bsub[k][tg];
            acc[0][0] = fmaf(a.x, b.x, acc[0][0]);
            acc[0][1] = fmaf(a.x, b.y, acc[0][1]);
            acc[0][2] = fmaf(a.x, b.z, acc[0][2]);
            acc[0][3] = fmaf(a.x, b.w, acc[0][3]);
            acc[1][0] = fmaf(a.y, b.x, acc[1][0]);
            acc[1][1] = fmaf(a.y, b.y, acc[1][1]);
            acc[1][2] = fmaf(a.y, b.z, acc[1][2]);
            acc[1][3] = fmaf(a.y, b.w, acc[1][3]);
            acc[2][0] = fmaf(a.z, b.x, acc[2][0]);
            acc[2][1] = fmaf(a.z, b.y, acc[2][1]);
            acc[2][2] = fmaf(a.z, b.z, acc[2][2]);
            acc[2][3] = fmaf(a.z, b.w, acc[2][3]);
            acc[3][0] = fmaf(a.w, b.x, acc[3][0]);
            acc[3][1] = fmaf(a.w, b.y, acc[3][1]);
            acc[3][2] = fmaf(a.w, b.z, acc[3][2]);
            acc[3][3] = fmaf(a.w, b.w, acc[3][3]);
        }
    }
    float* out = Xg + ((size_t)dir * 8192 + m0) * 1024 + n0;
#pragma unroll
    for (int i = 0; i < 4; ++i) {
        float4 v = make_float4(acc[i][0], acc[i][1], acc[i][2], acc[i][3]);
        *(float4*)&out[(size_t)(tm + i) * 1024 + tg] = v;
    }
}

// ---------------------------------------------------------------------------
// K2: bidirectional LSTM, one WG per (batch row, direction). 1024 threads;
// thread t owns gate t and keeps Whh[t,0:256] register-resident (256 VGPRs).
// h broadcast through LDS (double-buffered). f32 throughout, libm activations.
// ---------------------------------------------------------------------------
__global__ __launch_bounds__(1024, 1) void lstm_kernel(
    const float* __restrict__ Xg,    // [2][8192][1024]
    const float* __restrict__ Whh_f, const float* __restrict__ Whh_b,
    const float* __restrict__ b_f, const float* __restrict__ b_b,
    const int* __restrict__ lens,
    float* __restrict__ enc) {       // [B][S][512]
    const int wg = blockIdx.x;       // 0..127
    const int dir = wg & 1, b = wg >> 1;
    const int t = threadIdx.x;       // gate index 0..1023 (i|f|g|o blocks of 256)
    const float* Whh = dir ? Whh_b : Whh_f;

    float w[256];
    const float4* wrow = (const float4*)(Whh + (size_t)t * H_);
#pragma unroll
    for (int k = 0; k < 64; ++k) {
        float4 v = wrow[k];
        w[4 * k + 0] = v.x; w[4 * k + 1] = v.y;
        w[4 * k + 2] = v.z; w[4 * k + 3] = v.w;
    }
    const float bias = (dir ? b_b : b_f)[t];
    const int len = lens[b];

    __shared__ float h_sh[2][H_];
    __shared__ float g_sh[4 * H_];
    if (t < H_) h_sh[0][t] = 0.f;
    float c = 0.f;  // cell state, valid for t < 256
    __syncthreads();

    const float* xbase = Xg + (size_t)dir * 8192 * 1024 + (size_t)b * 1024 + t;
    int cur = 0;
    int xrow0 = dir ? (len - 1) : 0;   // len >= 1 guaranteed
    float xv = xbase[(size_t)xrow0 * (B_ * 1024)];
    int xrow = xrow0;

    for (int step = 0; step < S_; ++step) {
        // prefetch next step's input-gate term (hides latency under the dot)
        float xv_next = 0.f;
        if (step + 1 < S_) {
            int nstep = step + 1;
            int nrow = dir ? ((nstep < len) ? (len - 1 - nstep) : nstep) : nstep;
            xv_next = xbase[(size_t)nrow * (B_ * 1024)];
        }
        float acc = bias + xv;
        const float4* hp = (const float4*)h_sh[cur];
#pragma unroll
        for (int k = 0; k < 64; ++k) {
            float4 hv = hp[k];  // same-address broadcast for all lanes
            acc = fmaf(w[4 * k + 0], hv.x, acc);
            acc = fmaf(w[4 * k + 1], hv.y, acc);
            acc = fmaf(w[4 * k + 2], hv.z, acc);
            acc = fmaf(w[4 * k + 3], hv.w, acc);
        }
        // i,f,o -> sigmoid ; g -> tanh   (wave-uniform branch: blocks of 256)
        float act = (t >= 512 && t < 768) ? tanh_acc(acc) : sigmoid_acc(acc);
        g_sh[t] = act;
        __syncthreads();
        if (t < H_) {
            float iv = g_sh[t], fv = g_sh[H_ + t], gv = g_sh[2 * H_ + t], ov = g_sh[3 * H_ + t];
            c = fv * c + iv * gv;
            float h = ov * tanh_acc(c);
            h_sh[cur ^ 1][t] = h;
            int orow = dir ? xrow : step;  // rev_idx is an involution
            enc[((size_t)b * S_ + orow) * 512 + dir * H_ + t] = (orow < len) ? h : 0.f;
        }
        __syncthreads();
        cur ^= 1;
        xv = xv_next;
        int nstep = step + 1;
        xrow = dir ? ((nstep < len) ? (len - 1 - nstep) : nstep) : nstep;
    }
}

// ---------------------------------------------------------------------------
// K3: U = enc@Ua^T, W = enc@Wa^T  (8192 x 512 @ 512 x 30, twice)
// grid (4, 64): 32 enc rows per WG; weights k-chunked through LDS.
// ---------------------------------------------------------------------------
__global__ __launch_bounds__(256) void uw_kernel(
    const float* __restrict__ enc, const float* __restrict__ Ua,
    const float* __restrict__ Wa, float* __restrict__ U, float* __restrict__ Wout) {
    __shared__ float wgt[60][129];  // rows 0..29 Ua-chunk, 30..59 Wa-chunk
    __shared__ float erow[4][128];
    const int tid = threadIdx.x;
    const int b = blockIdx.y, s0 = blockIdx.x * 32;
    const int rl = tid >> 6;        // row-local 0..3
    const int d = tid & 63;
    const int dd = d & 31;          // output dim 0..31 (<30 active)
    const int isW = d >> 5;         // 0 -> U, 1 -> W
    float acc[8];
#pragma unroll
    for (int i = 0; i < 8; ++i) acc[i] = 0.f;

    for (int kk = 0; kk < 4; ++kk) {
        __syncthreads();  // previous wgt fully consumed
        for (int i = tid; i < 30 * 128; i += 256) {
            int r = i >> 7, k = i & 127;
            wgt[r][k] = Ua[(size_t)r * 512 + kk * 128 + k];
            wgt[r + 30][k] = Wa[(size_t)r * 512 + kk * 128 + k];
        }
        for (int chunk = 0; chunk < 8; ++chunk) {
            __syncthreads();
            for (int i = tid; i < 4 * 128; i += 256) {
                int r = i >> 7, k = i & 127;
                erow[r][k] = enc[((size_t)b * S_ + (s0 + chunk * 4 + r)) * 512 + kk * 128 + k];
            }
            __syncthreads();
            if (dd < HID_) {
                const float* wr = wgt[dd + 30 * isW];
                const float* er = erow[rl];
                float a = acc[chunk];
#pragma unroll
                for (int k = 0; k < 128; ++k) a = fmaf(er[k], wr[k], a);
                acc[chunk] = a;
            }
        }
    }
    if (dd < HID_) {
        float* dst = isW ? Wout : U;
#pragma unroll
        for (int chunk = 0; chunk < 8; ++chunk)
            dst[((size_t)b * S_ + (s0 + chunk * 4 + rl)) * 32 + dd] = acc[chunk];
    }
}

// ---------------------------------------------------------------------------
// K4: scores[b,i,j] = sum_d va[d] * tanh(u[b,i,d] + w[b,j,d])
//     preds = (sigmoid_f32(score) >= 0.5) — mimics reference boundary exactly
// grid (4, 64): 32 i-rows x all 128 j per WG.
// ---------------------------------------------------------------------------
__global__ __launch_bounds__(256) void scores_kernel(
    const float* __restrict__ U, const float* __restrict__ W,
    const float* __restrict__ va,
    float* __restrict__ scores, float* __restrict__ preds) {
    __shared__ float w_sh[128][31];
    const int b = blockIdx.y, i0 = blockIdx.x * 32;
    const int tid = threadIdx.x;

    float va_r[HID_];
#pragma unroll
    for (int d2 = 0; d2 < HID_; ++d2) va_r[d2] = va[d2];  // uniform -> s_load

    for (int i = tid; i < 128 * HID_; i += 256) {
        int r = i / HID_, d2 = i - r * HID_;
        w_sh[r][d2] = W[((size_t)b * S_ + r) * 32 + d2];
    }
    __syncthreads();

    const int il = tid >> 3;        // 0..31
    const int jb = (tid & 7) * 16;  // j base
    float u_r[HID_];
    const float* urow = U + ((size_t)b * S_ + i0 + il) * 32;
#pragma unroll
    for (int d2 = 0; d2 < HID_; ++d2) u_r[d2] = urow[d2];

    const size_t obase = ((size_t)b * S_ + (i0 + il)) * S_;
    for (int jj = 0; jj < 16; ++jj) {
        int j = jb + jj;
        float acc = 0.f;
#pragma unroll
        for (int d2 = 0; d2 < HID_; ++d2)
            acc = fmaf(va_r[d2], tanh_acc(u_r[d2] + w_sh[j][d2]), acc);
        scores[obase + j] = acc;
        preds[obase + j] = (sigmoid_acc(acc) >= 0.5f) ? 1.f : 0.f;
    }
}

// ---------------------------------------------------------------------------
// Workspace layout (bytes):
//   Xg  @ 0          : 2*8192*1024*4 = 67,108,864
//   enc @ 67,108,864 : 64*128*512*4  = 16,777,216
//   U   @ 83,886,080 : 8192*32*4     =  1,048,576
//   W   @ 84,934,656 : 8192*32*4     =  1,048,576   (total ~86 MB)
// ---------------------------------------------------------------------------
extern "C" void kernel_launch(void* const* d_in, const int* in_sizes, int n_in,
                              void* d_out, int out_size, void* d_ws, size_t ws_size,
                              hipStream_t stream) {
    (void)in_sizes; (void)n_in; (void)out_size; (void)ws_size;
    const int* concepts = (const int*)d_in[0];
    const int* lens = (const int*)d_in[1];
    const float* embedding = (const float*)d_in[2];
    const float* Wih_f = (const float*)d_in[3];
    const float* Whh_f = (const float*)d_in[4];
    const float* b_f = (const float*)d_in[5];
    const float* Wih_b = (const float*)d_in[6];
    const float* Whh_b = (const float*)d_in[7];
    const float* b_b = (const float*)d_in[8];
    const float* Ua = (const float*)d_in[9];
    const float* Wa = (const float*)d_in[10];
    const float* va = (const float*)d_in[11];

    char* ws = (char*)d_ws;
    float* Xg = (float*)(ws + 0);
    float* enc = (float*)(ws + 67108864);
    float* U = (float*)(ws + 83886080);
    float* W = (float*)(ws + 84934656);

    float* scores = (float*)d_out;
    float* preds = scores + (size_t)B_ * S_ * S_;

    hipLaunchKernelGGL(gemm_f32_kernel, dim3(2048, 2), dim3(256), 0, stream,
                       concepts, embedding, Wih_f, Wih_b, Xg);
    hipLaunchKernelGGL(lstm_kernel, dim3(128), dim3(1024), 0, stream,
                       Xg, Whh_f, Whh_b, b_f, b_b, lens, enc);
    hipLaunchKernelGGL(uw_kernel, dim3(4, 64), dim3(256), 0, stream,
                       enc, Ua, Wa, U, W);
    hipLaunchKernelGGL(scores_kernel, dim3(4, 64), dim3(256), 0, stream,
                       U, W, va, scores, preds);
}